// Round 14
// baseline (199.833 us; speedup 1.0000x reference)
//
#include <hip/hip_runtime.h>
#include <hip/hip_bf16.h>
#include <math.h>

#define S_LEN 2048
#define HIDN  1024
#define K_DIM 1024
#define NHEAD 16
#define NKVH  4
#define HD    64

typedef __bf16 bf16x8 __attribute__((ext_vector_type(8)));
typedef float  f32x4  __attribute__((ext_vector_type(4)));
typedef float  f32x16 __attribute__((ext_vector_type(16)));

static __device__ __forceinline__ unsigned short f2bf(float f) {
  union { float f; unsigned u; } v; v.f = f;
  unsigned u = v.u;
  u += 0x7fffu + ((u >> 16) & 1u);
  return (unsigned short)(u >> 16);
}

static __device__ __forceinline__ void gload_lds16(const unsigned short* g, unsigned short* l) {
  __builtin_amdgcn_global_load_lds((const __attribute__((address_space(1))) void*)g,
                                   (__attribute__((address_space(3))) void*)l, 16, 0, 0);
}

// ---------------- prep: fp32->bf16 conversions + cos/sin table ----------------
__global__ __launch_bounds__(256) void prep_kernel(const float* __restrict__ hs,
                                                   const float* __restrict__ Wq,
                                                   const float* __restrict__ Wk,
                                                   const float* __restrict__ Wv,
                                                   const float* __restrict__ Wo,
                                                   const int* __restrict__ pos,
                                                   unsigned short* __restrict__ hsb,
                                                   unsigned short* __restrict__ Wqkv,
                                                   unsigned short* __restrict__ Wob,
                                                   float2* __restrict__ cstab) {
  const int gid = blockIdx.x * 256 + threadIdx.x;
  if (gid < 1179648) {
    const float* src; unsigned short* dst; int i;
    if (gid < 524288)       { src = hs; dst = hsb;            i = gid; }
    else if (gid < 786432)  { src = Wq; dst = Wqkv;           i = gid - 524288; }
    else if (gid < 851968)  { src = Wk; dst = Wqkv + 1048576; i = gid - 786432; }
    else if (gid < 917504)  { src = Wv; dst = Wqkv + 1310720; i = gid - 851968; }
    else                    { src = Wo; dst = Wob;            i = gid - 917504; }
    float4 v = *(const float4*)(src + (size_t)i * 4);
    ushort4 u;
    u.x = f2bf(v.x); u.y = f2bf(v.y); u.z = f2bf(v.z); u.w = f2bf(v.w);
    *(ushort4*)(dst + (size_t)i * 4) = u;
  } else {
    int e = gid - 1179648;                 // 2048*32 entries
    int s = e >> 5, ir = e & 31;
    float p = (float)pos[s];
    float ang = p * __expf(-(float)ir * 0.28782314f);   // ln(10000)/32
    float c, sn;
    sincosf(ang, &sn, &c);
    cstab[e] = make_float2(c, sn);
  }
}

// ---------------- GEMM: C[m][n] = sum_k A[m][k] * B[n][k], bf16 MFMA ----------------
// Tile 64(M) x 128(N) x 64(K); 4 waves (2m x 2n), wave tile 32x64.
// ROPE epilogue writes Q/K rotated AND V^T directly (transpose fused).
template <bool ROPE>
__global__ __launch_bounds__(256, 2) void gemm_kernel(const unsigned short* __restrict__ A,
                                                      const unsigned short* __restrict__ B,
                                                      float* __restrict__ C,
                                                      const float2* __restrict__ cstab,
                                                      unsigned short* __restrict__ Qr,
                                                      unsigned short* __restrict__ Kr,
                                                      unsigned short* __restrict__ Vt) {
  __shared__ unsigned short As[2][64][64];
  __shared__ unsigned short Bs[2][128][64];
  const int m0 = blockIdx.x * 64, n0 = blockIdx.y * 128;
  const int t = threadIdx.x, w = t >> 6, lane = t & 63;
  const int lr = lane & 15, lg = lane >> 4;
  const int m_off = (w & 1) * 32, n_off = (w >> 1) * 64;
  const int rsub = lane >> 3;
  const int cole = ((lane & 7) * 8) ^ (rsub << 3);
  f32x4 acc[2][4] = {};

#define GSTAGE(b, kt) do {                                                     \
    _Pragma("unroll")                                                          \
    for (int c = 0; c < 2; ++c) {                                              \
      int ch = w * 2 + c;                                                      \
      gload_lds16(A + (size_t)(m0 + ch * 8 + rsub) * K_DIM + (kt) * 64 + cole, \
                  &As[b][0][0] + ch * 512);                                    \
    }                                                                          \
    _Pragma("unroll")                                                          \
    for (int c = 0; c < 4; ++c) {                                              \
      int ch = w * 4 + c;                                                      \
      gload_lds16(B + (size_t)(n0 + ch * 8 + rsub) * K_DIM + (kt) * 64 + cole, \
                  &Bs[b][0][0] + ch * 512);                                    \
    }                                                                          \
  } while (0)

  int cur = 0;
  GSTAGE(0, 0);
  for (int kt = 0; kt < 16; ++kt) {
    __syncthreads();
    if (kt + 1 < 16) GSTAGE(cur ^ 1, kt + 1);
#pragma unroll
    for (int kc = 0; kc < 2; ++kc) {
      bf16x8 af[2], bfg[4];
#pragma unroll
      for (int i = 0; i < 2; ++i) {
        int row = m_off + i * 16 + lr;
        af[i] = *(const bf16x8*)((const char*)&As[cur][0][0] + row * 128 +
                                 ((kc * 64 + lg * 16) ^ ((lr & 7) << 4)));
      }
#pragma unroll
      for (int jj = 0; jj < 4; ++jj) {
        int row = n_off + jj * 16 + lr;
        bfg[jj] = *(const bf16x8*)((const char*)&Bs[cur][0][0] + row * 128 +
                                   ((kc * 64 + lg * 16) ^ ((lr & 7) << 4)));
      }
#pragma unroll
      for (int i = 0; i < 2; ++i)
#pragma unroll
        for (int jj = 0; jj < 4; ++jj)
          acc[i][jj] = __builtin_amdgcn_mfma_f32_16x16x32_bf16(af[i], bfg[jj], acc[i][jj], 0, 0, 0);
    }
    cur ^= 1;
  }

  if constexpr (ROPE) {
    const int col64 = n0 + n_off;
    const int hh = col64 >> 6;   // 0..15 Q, 16..19 K, 20..23 V
#pragma unroll
    for (int i = 0; i < 2; ++i) {
      if (hh < 20) {
#pragma unroll
        for (int r = 0; r < 4; ++r) {
          int srow = m0 + m_off + i * 16 + lg * 4 + r;
          unsigned short* dst = (hh < 16) ? (Qr + ((size_t)hh * S_LEN + srow) * HD)
                                          : (Kr + ((size_t)(hh - 16) * S_LEN + srow) * HD);
          float sc = (hh < 16) ? 0.125f : 1.0f;   // fold 1/sqrt(64) into Q (exact)
#pragma unroll
          for (int jj = 0; jj < 2; ++jj) {
            int d0 = jj * 16 + lr;
            float2 cs = cstab[(size_t)srow * 32 + d0];
            float v0 = acc[i][jj][r] * sc, v1 = acc[i][jj + 2][r] * sc;
            dst[d0]      = f2bf(v0 * cs.x - v1 * cs.y);
            dst[d0 + 32] = f2bf(v1 * cs.x + v0 * cs.y);
          }
        }
      } else {
        // V^T fused: Vt[kh][d][s], 4 consecutive s per ushort4
        const int khv = (col64 - 1280) >> 6;
        const int s_base = m0 + m_off + i * 16 + lg * 4;
#pragma unroll
        for (int jj = 0; jj < 4; ++jj) {
          int d = jj * 16 + lr;
          ushort4 u;
          u.x = f2bf(acc[i][jj][0]);
          u.y = f2bf(acc[i][jj][1]);
          u.z = f2bf(acc[i][jj][2]);
          u.w = f2bf(acc[i][jj][3]);
          *(ushort4*)(Vt + ((size_t)khv * HD + d) * S_LEN + s_base) = u;
        }
      }
    }
  } else {
#pragma unroll
    for (int i = 0; i < 2; ++i)
#pragma unroll
      for (int jj = 0; jj < 4; ++jj)
#pragma unroll
        for (int r = 0; r < 4; ++r)
          C[(size_t)(m0 + m_off + i * 16 + lg * 4 + r) * 1024 + n0 + n_off + jj * 16 + lr] =
              acc[i][jj][r];
  }
}

// ---------------- Flash attention: 32x32 MFMA, swapped QK^T, in-register P ----------------
// R10 structure + FUSED last-finisher merge: after the partial store, each chunk
// block counts in via device-scope atomic; the last chunk for a (h,qt) tile runs
// the merge inline (overlaps other tiles' compute; removes the merge launch).
__global__ __launch_bounds__(256, 4) void attn_part(const unsigned short* __restrict__ Qr,
                                                    const unsigned short* __restrict__ Kr,
                                                    const unsigned short* __restrict__ Vt,
                                                    unsigned short* __restrict__ Ob,
                                                    float* __restrict__ Opart,
                                                    float* __restrict__ Mlpart,
                                                    unsigned* __restrict__ cnt) {
  __shared__ unsigned short Ks[2][64][64];
  __shared__ unsigned short Vs[2][64][64];   // V^T [d][k]
  __shared__ unsigned s_old;
  const int bid = blockIdx.x;
  const int h = bid & 15;
  const int j = bid >> 4;                    // 0..39, big jobs first
  int qt, ck;
  if (j < 16)      { qt = 15 - (j >> 2); ck = j & 3; }
  else if (j < 28) { int e = j - 16; int d3 = e / 3; qt = 11 - d3; ck = e - d3 * 3; }
  else if (j < 36) { int e = j - 28; qt = 7 - (e >> 1); ck = e & 1; }
  else             { qt = 39 - j; ck = 0; }
  const int kh = h >> 2;
  const int nkt_all = 2 * qt + 2;
  const int nch = (2 * qt + 9) >> 3;
  const int kt0 = ck * 8;
  const int kt1 = (kt0 + 8 < nkt_all) ? kt0 + 8 : nkt_all;

  const int t = threadIdx.x, w = t >> 6, lane = t & 63;
  const int ql = lane & 31, hi = lane >> 5;
  const int q = qt * 128 + w * 32 + ql;      // absolute q row (2 lanes per q)
  const int qwave_max = qt * 128 + w * 32 + 31;

  const unsigned short* Kh = Kr + (size_t)kh * S_LEN * HD;
  const unsigned short* Vh = Vt + (size_t)kh * HD * S_LEN;

  bf16x8 qf[4];
#pragma unroll
  for (int c = 0; c < 4; ++c)
    qf[c] = *(const bf16x8*)(Qr + ((size_t)h * S_LEN + q) * HD + c * 16 + hi * 8);

  const int rsub = lane >> 3;
  const int cole = ((lane & 7) * 8) ^ (rsub << 3);

#define ASTAGE(b, kt) do {                                                           \
    int k0s = (kt) * 64;                                                             \
    _Pragma("unroll")                                                                \
    for (int c = 0; c < 4; ++c) {                                                    \
      int ch = w * 4 + c;                                                            \
      if (ch < 8)                                                                    \
        gload_lds16(Kh + (size_t)(k0s + ch * 8 + rsub) * HD + cole,                  \
                    &Ks[b][0][0] + ch * 512);                                        \
      else                                                                           \
        gload_lds16(Vh + (size_t)((ch - 8) * 8 + rsub) * S_LEN + k0s + cole,         \
                    &Vs[b][0][0] + (ch - 8) * 512);                                  \
    }                                                                                \
  } while (0)

  float m_run = -1e30f, l_run = 0.f;
  f32x16 oacc[2] = {};
  int cur = 0;
  ASTAGE(0, kt0);
  for (int kt = kt0; kt < kt1; ++kt) {
    __syncthreads();
    if (kt + 1 < kt1) ASTAGE(cur ^ 1, kt + 1);
    const int k0 = kt * 64;
    if (k0 <= qwave_max) {                   // skip fully-masked tiles (wave-uniform)
      f32x16 sacc[2] = {};
      __builtin_amdgcn_s_setprio(1);
#pragma unroll
      for (int tt = 0; tt < 2; ++tt)
#pragma unroll
        for (int c = 0; c < 4; ++c) {
          int row = tt * 32 + ql;
          bf16x8 kf = *(const bf16x8*)((const char*)&Ks[cur][0][0] + row * 128 +
                                       ((c * 32 + hi * 16) ^ ((ql & 7) << 4)));
          sacc[tt] = __builtin_amdgcn_mfma_f32_32x32x16_bf16(kf, qf[c], sacc[tt], 0, 0, 0);
        }
      __builtin_amdgcn_s_setprio(0);

      float p[32];
#pragma unroll
      for (int tt = 0; tt < 2; ++tt)
#pragma unroll
        for (int e = 0; e < 16; ++e) p[tt * 16 + e] = sacc[tt][e];

      if (k0 + 63 > q) {                     // diagonal tile: per-element mask
#pragma unroll
        for (int tt = 0; tt < 2; ++tt)
#pragma unroll
          for (int e = 0; e < 16; ++e) {
            int kl = tt * 32 + (e & 3) + 8 * (e >> 2) + 4 * hi;
            if (k0 + kl > q) p[tt * 16 + e] = -1e30f;
          }
      }

      float mx = p[0];
#pragma unroll
      for (int e = 1; e < 32; ++e) mx = fmaxf(mx, p[e]);
      mx = fmaxf(mx, __shfl_xor(mx, 32));

      if (__any(mx > m_run + 8.0f)) {        // defer-max (T13)
        float mnew = fmaxf(m_run, mx);
        float f = __expf(m_run - mnew);
        l_run *= f;
        oacc[0] *= f; oacc[1] *= f;
        m_run = mnew;
      }

      float lsum = 0.f;
#pragma unroll
      for (int e = 0; e < 32; ++e) { p[e] = __expf(p[e] - m_run); lsum += p[e]; }
      lsum += __shfl_xor(lsum, 32);
      l_run += lsum;

      unsigned g[16];
#pragma unroll
      for (int i = 0; i < 16; ++i) {
        union { __hip_bfloat162 b; unsigned u; } cv;
        cv.b = __float22bfloat162_rn(make_float2(p[2 * i], p[2 * i + 1]));
        g[i] = cv.u;
      }
#pragma unroll
      for (int b4 = 0; b4 < 16; b4 += 8) {
        asm volatile("v_permlane32_swap_b32 %0, %1" : "+v"(g[b4 + 0]), "+v"(g[b4 + 2]));
        asm volatile("v_permlane32_swap_b32 %0, %1" : "+v"(g[b4 + 1]), "+v"(g[b4 + 3]));
        asm volatile("v_permlane32_swap_b32 %0, %1" : "+v"(g[b4 + 4]), "+v"(g[b4 + 6]));
        asm volatile("v_permlane32_swap_b32 %0, %1" : "+v"(g[b4 + 5]), "+v"(g[b4 + 7]));
      }

#pragma unroll
      for (int s = 0; s < 4; ++s) {
        union { bf16x8 v; unsigned u[4]; } pf;
        pf.u[0] = g[s * 4 + 0]; pf.u[1] = g[s * 4 + 1];
        pf.u[2] = g[s * 4 + 2]; pf.u[3] = g[s * 4 + 3];
        __builtin_amdgcn_s_setprio(1);
#pragma unroll
        for (int dt = 0; dt < 2; ++dt) {
          int row = dt * 32 + ql;
          bf16x8 vf = *(const bf16x8*)((const char*)&Vs[cur][0][0] + row * 128 +
                                       ((s * 32 + hi * 16) ^ ((ql & 7) << 4)));
          oacc[dt] = __builtin_amdgcn_mfma_f32_32x32x16_bf16(vf, pf.v, oacc[dt], 0, 0, 0);
        }
        __builtin_amdgcn_s_setprio(0);
      }
    }
    cur ^= 1;
  }

  if (nch == 1) {
    float inv = 1.f / l_run;
#pragma unroll
    for (int dt = 0; dt < 2; ++dt)
#pragma unroll
      for (int gg = 0; gg < 4; ++gg) {
        ushort4 u;
        u.x = f2bf(oacc[dt][gg * 4 + 0] * inv);
        u.y = f2bf(oacc[dt][gg * 4 + 1] * inv);
        u.z = f2bf(oacc[dt][gg * 4 + 2] * inv);
        u.w = f2bf(oacc[dt][gg * 4 + 3] * inv);
        int d0 = dt * 32 + 8 * gg + 4 * hi;
        *(ushort4*)(Ob + (size_t)q * HIDN + h * HD + d0) = u;
      }
  } else {
    const int slot = (h * 16 + qt) * 4 + ck;
    float* ob = Opart + (size_t)slot * 8192 + t * 32;
#pragma unroll
    for (int dt = 0; dt < 2; ++dt)
#pragma unroll
      for (int gg = 0; gg < 4; ++gg) {
        f32x4 v4;
        v4[0] = oacc[dt][gg * 4 + 0]; v4[1] = oacc[dt][gg * 4 + 1];
        v4[2] = oacc[dt][gg * 4 + 2]; v4[3] = oacc[dt][gg * 4 + 3];
        *(f32x4*)(ob + dt * 16 + gg * 4) = v4;
      }
    if (hi == 0)
      *(float2*)(Mlpart + ((size_t)slot * 128 + w * 32 + ql) * 2) = make_float2(m_run, l_run);

    // ---- fused last-finisher merge (split-K semaphore pattern) ----
    __threadfence();                         // release: this block's partials visible
    __syncthreads();                         // all threads' stores + fences done
    if (t == 0) s_old = atomicAdd(&cnt[h * 16 + qt], 1u);
    __syncthreads();
    if (s_old == (unsigned)(nch - 1)) {      // last chunk of this (h,qt): merge now
      __threadfence();                       // acquire: other chunks' partials visible
      const int slotb = (h * 16 + qt) * 4;
      const int mql = t & 31, mhi = (t >> 5) & 1, mw = t >> 6;
      const int q_l = mw * 32 + mql;
      const int qq = qt * 128 + q_l;
      float mc[4], lc[4], mstar = -1e30f;
      for (int c = 0; c < 4; ++c)
        if (c < nch) {
          float2 ml = *(const float2*)(Mlpart + ((size_t)(slotb + c) * 128 + q_l) * 2);
          mc[c] = ml.x; lc[c] = ml.y;
          mstar = fmaxf(mstar, ml.x);
        }
      float wgt[4], msum = 0.f;
      for (int c = 0; c < 4; ++c)
        if (c < nch) { wgt[c] = __expf(mc[c] - mstar); msum += wgt[c] * lc[c]; }
      const float minv = 1.f / msum;
      for (int g2 = 0; g2 < 8; ++g2) {
        f32x4 a = {};
        for (int c = 0; c < 4; ++c)
          if (c < nch) {
            f32x4 v = *(const f32x4*)(Opart + (size_t)(slotb + c) * 8192 + t * 32 + g2 * 4);
            a += v * wgt[c];
          }
        int dt = g2 >> 2, gg = g2 & 3;
        int d0 = dt * 32 + 8 * gg + 4 * mhi;
        ushort4 u;
        u.x = f2bf(a[0] * minv); u.y = f2bf(a[1] * minv);
        u.z = f2bf(a[2] * minv); u.w = f2bf(a[3] * minv);
        *(ushort4*)(Ob + (size_t)qq * HIDN + h * HD + d0) = u;
      }
    }
  }
}

extern "C" void kernel_launch(void* const* d_in, const int* in_sizes, int n_in,
                              void* d_out, int out_size, void* d_ws, size_t ws_size,
                              hipStream_t stream) {
  const float* hs = (const float*)d_in[0];
  // d_in[1] = attention_mask (deterministic causal; applied analytically)
  const int* pos = (const int*)d_in[2];
  const float* Wq = (const float*)d_in[3];
  const float* Wk = (const float*)d_in[4];
  const float* Wv = (const float*)d_in[5];
  const float* Wo = (const float*)d_in[6];
  float* out = (float*)d_out;

  char* ws = (char*)d_ws;
  unsigned short* hsb   = (unsigned short*)(ws);
  unsigned short* Wqkv  = (unsigned short*)(ws + 4194304);
  unsigned short* Wob   = (unsigned short*)(ws + 7340032);
  float2*         cstab = (float2*)(ws + 9437184);
  unsigned short* Qr    = (unsigned short*)(ws + 10485760);
  unsigned short* Kr    = (unsigned short*)(ws + 14680064);
  unsigned short* Vt    = (unsigned short*)(ws + 16777216);
  unsigned short* Ob    = (unsigned short*)(ws + 17825792);
  float*          Opart = (float*)(ws + 22020096);   // 1024 slots * 32KB = 32MB
  float*          Mlpart= (float*)(ws + 55574528);   // 1024 * 128 * 8B = 1MB
  unsigned*       cnt   = (unsigned*)(ws + 56623104); // 256 * 4B chunk counters

  hipMemsetAsync(cnt, 0, 256 * sizeof(unsigned), stream);  // reset semaphores (capturable)

  dim3 blk(256);
  prep_kernel<<<4864, blk, 0, stream>>>(hs, Wq, Wk, Wv, Wo, pos, hsb, Wqkv, Wob, cstab);
  gemm_kernel<true><<<dim3(32, 12), blk, 0, stream>>>(hsb, Wqkv, nullptr, cstab, Qr, Kr, Vt);
  attn_part<<<640, blk, 0, stream>>>(Qr, Kr, Vt, Ob, Opart, Mlpart, cnt);
  gemm_kernel<false><<<dim3(32, 8), blk, 0, stream>>>(Ob, Wob, out, nullptr, nullptr, nullptr, nullptr);
}

// Round 15
// 86.089 us; speedup vs baseline: 2.3212x; 2.3212x over previous
//
#include <hip/hip_runtime.h>
#include <hip/hip_bf16.h>
#include <math.h>

#define S_LEN 2048
#define HIDN  1024
#define K_DIM 1024
#define NHEAD 16
#define NKVH  4
#define HD    64

typedef __bf16 bf16x8 __attribute__((ext_vector_type(8)));
typedef float  f32x4  __attribute__((ext_vector_type(4)));
typedef float  f32x16 __attribute__((ext_vector_type(16)));

static __device__ __forceinline__ unsigned short f2bf(float f) {
  union { float f; unsigned u; } v; v.f = f;
  unsigned u = v.u;
  u += 0x7fffu + ((u >> 16) & 1u);
  return (unsigned short)(u >> 16);
}

static __device__ __forceinline__ void gload_lds16(const unsigned short* g, unsigned short* l) {
  __builtin_amdgcn_global_load_lds((const __attribute__((address_space(1))) void*)g,
                                   (__attribute__((address_space(3))) void*)l, 16, 0, 0);
}

// ---------------- prep: fp32->bf16 conversions + cos/sin table ----------------
__global__ __launch_bounds__(256) void prep_kernel(const float* __restrict__ hs,
                                                   const float* __restrict__ Wq,
                                                   const float* __restrict__ Wk,
                                                   const float* __restrict__ Wv,
                                                   const float* __restrict__ Wo,
                                                   const int* __restrict__ pos,
                                                   unsigned short* __restrict__ hsb,
                                                   unsigned short* __restrict__ Wqkv,
                                                   unsigned short* __restrict__ Wob,
                                                   float2* __restrict__ cstab) {
  const int gid = blockIdx.x * 256 + threadIdx.x;
  if (gid < 1179648) {
    const float* src; unsigned short* dst; int i;
    if (gid < 524288)       { src = hs; dst = hsb;            i = gid; }
    else if (gid < 786432)  { src = Wq; dst = Wqkv;           i = gid - 524288; }
    else if (gid < 851968)  { src = Wk; dst = Wqkv + 1048576; i = gid - 786432; }
    else if (gid < 917504)  { src = Wv; dst = Wqkv + 1310720; i = gid - 851968; }
    else                    { src = Wo; dst = Wob;            i = gid - 917504; }
    float4 v = *(const float4*)(src + (size_t)i * 4);
    ushort4 u;
    u.x = f2bf(v.x); u.y = f2bf(v.y); u.z = f2bf(v.z); u.w = f2bf(v.w);
    *(ushort4*)(dst + (size_t)i * 4) = u;
  } else {
    int e = gid - 1179648;                 // 2048*32 entries
    int s = e >> 5, ir = e & 31;
    float p = (float)pos[s];
    float ang = p * __expf(-(float)ir * 0.28782314f);   // ln(10000)/32
    float c, sn;
    sincosf(ang, &sn, &c);
    cstab[e] = make_float2(c, sn);
  }
}

// ---------------- GEMM: C[m][n] = sum_k A[m][k] * B[n][k], bf16 MFMA ----------------
// Tile 64(M) x 128(N) x 64(K); 4 waves (2m x 2n), wave tile 32x64.
// ROPE epilogue writes Q/K rotated AND V^T directly (transpose fused).
template <bool ROPE>
__global__ __launch_bounds__(256, 2) void gemm_kernel(const unsigned short* __restrict__ A,
                                                      const unsigned short* __restrict__ B,
                                                      float* __restrict__ C,
                                                      const float2* __restrict__ cstab,
                                                      unsigned short* __restrict__ Qr,
                                                      unsigned short* __restrict__ Kr,
                                                      unsigned short* __restrict__ Vt) {
  __shared__ unsigned short As[2][64][64];
  __shared__ unsigned short Bs[2][128][64];
  const int m0 = blockIdx.x * 64, n0 = blockIdx.y * 128;
  const int t = threadIdx.x, w = t >> 6, lane = t & 63;
  const int lr = lane & 15, lg = lane >> 4;
  const int m_off = (w & 1) * 32, n_off = (w >> 1) * 64;
  const int rsub = lane >> 3;
  const int cole = ((lane & 7) * 8) ^ (rsub << 3);
  f32x4 acc[2][4] = {};

#define GSTAGE(b, kt) do {                                                     \
    _Pragma("unroll")                                                          \
    for (int c = 0; c < 2; ++c) {                                              \
      int ch = w * 2 + c;                                                      \
      gload_lds16(A + (size_t)(m0 + ch * 8 + rsub) * K_DIM + (kt) * 64 + cole, \
                  &As[b][0][0] + ch * 512);                                    \
    }                                                                          \
    _Pragma("unroll")                                                          \
    for (int c = 0; c < 4; ++c) {                                              \
      int ch = w * 4 + c;                                                      \
      gload_lds16(B + (size_t)(n0 + ch * 8 + rsub) * K_DIM + (kt) * 64 + cole, \
                  &Bs[b][0][0] + ch * 512);                                    \
    }                                                                          \
  } while (0)

  int cur = 0;
  GSTAGE(0, 0);
  for (int kt = 0; kt < 16; ++kt) {
    __syncthreads();
    if (kt + 1 < 16) GSTAGE(cur ^ 1, kt + 1);
#pragma unroll
    for (int kc = 0; kc < 2; ++kc) {
      bf16x8 af[2], bfg[4];
#pragma unroll
      for (int i = 0; i < 2; ++i) {
        int row = m_off + i * 16 + lr;
        af[i] = *(const bf16x8*)((const char*)&As[cur][0][0] + row * 128 +
                                 ((kc * 64 + lg * 16) ^ ((lr & 7) << 4)));
      }
#pragma unroll
      for (int jj = 0; jj < 4; ++jj) {
        int row = n_off + jj * 16 + lr;
        bfg[jj] = *(const bf16x8*)((const char*)&Bs[cur][0][0] + row * 128 +
                                   ((kc * 64 + lg * 16) ^ ((lr & 7) << 4)));
      }
#pragma unroll
      for (int i = 0; i < 2; ++i)
#pragma unroll
        for (int jj = 0; jj < 4; ++jj)
          acc[i][jj] = __builtin_amdgcn_mfma_f32_16x16x32_bf16(af[i], bfg[jj], acc[i][jj], 0, 0, 0);
    }
    cur ^= 1;
  }

  if constexpr (ROPE) {
    const int col64 = n0 + n_off;
    const int hh = col64 >> 6;   // 0..15 Q, 16..19 K, 20..23 V
#pragma unroll
    for (int i = 0; i < 2; ++i) {
      if (hh < 20) {
#pragma unroll
        for (int r = 0; r < 4; ++r) {
          int srow = m0 + m_off + i * 16 + lg * 4 + r;
          unsigned short* dst = (hh < 16) ? (Qr + ((size_t)hh * S_LEN + srow) * HD)
                                          : (Kr + ((size_t)(hh - 16) * S_LEN + srow) * HD);
          float sc = (hh < 16) ? 0.125f : 1.0f;   // fold 1/sqrt(64) into Q (exact)
#pragma unroll
          for (int jj = 0; jj < 2; ++jj) {
            int d0 = jj * 16 + lr;
            float2 cs = cstab[(size_t)srow * 32 + d0];
            float v0 = acc[i][jj][r] * sc, v1 = acc[i][jj + 2][r] * sc;
            dst[d0]      = f2bf(v0 * cs.x - v1 * cs.y);
            dst[d0 + 32] = f2bf(v1 * cs.x + v0 * cs.y);
          }
        }
      } else {
        // V^T fused: Vt[kh][d][s], 4 consecutive s per ushort4
        const int khv = (col64 - 1280) >> 6;
        const int s_base = m0 + m_off + i * 16 + lg * 4;
#pragma unroll
        for (int jj = 0; jj < 4; ++jj) {
          int d = jj * 16 + lr;
          ushort4 u;
          u.x = f2bf(acc[i][jj][0]);
          u.y = f2bf(acc[i][jj][1]);
          u.z = f2bf(acc[i][jj][2]);
          u.w = f2bf(acc[i][jj][3]);
          *(ushort4*)(Vt + ((size_t)khv * HD + d) * S_LEN + s_base) = u;
        }
      }
    }
  } else {
#pragma unroll
    for (int i = 0; i < 2; ++i)
#pragma unroll
      for (int jj = 0; jj < 4; ++jj)
#pragma unroll
        for (int r = 0; r < 4; ++r)
          C[(size_t)(m0 + m_off + i * 16 + lg * 4 + r) * 1024 + n0 + n_off + jj * 16 + lr] =
              acc[i][jj][r];
  }
}

// ---------------- Flash attention: 32x32 MFMA, swapped QK^T, in-register P ----------------
// Best-known config: block = (head, 128-q tile, chunk of <=8 k-tiles),
// 4 waves x 32 q-rows, LDS-staged K/V^T, cvt_pk + permlane32_swap P-transpose.
__global__ __launch_bounds__(256, 4) void attn_part(const unsigned short* __restrict__ Qr,
                                                    const unsigned short* __restrict__ Kr,
                                                    const unsigned short* __restrict__ Vt,
                                                    unsigned short* __restrict__ Ob,
                                                    float* __restrict__ Opart,
                                                    float* __restrict__ Mlpart) {
  __shared__ unsigned short Ks[2][64][64];
  __shared__ unsigned short Vs[2][64][64];   // V^T [d][k]
  const int bid = blockIdx.x;
  const int h = bid & 15;
  const int j = bid >> 4;                    // 0..39, big jobs first
  int qt, ck;
  if (j < 16)      { qt = 15 - (j >> 2); ck = j & 3; }
  else if (j < 28) { int e = j - 16; int d3 = e / 3; qt = 11 - d3; ck = e - d3 * 3; }
  else if (j < 36) { int e = j - 28; qt = 7 - (e >> 1); ck = e & 1; }
  else             { qt = 39 - j; ck = 0; }
  const int kh = h >> 2;
  const int nkt_all = 2 * qt + 2;
  const int nch = (2 * qt + 9) >> 3;
  const int kt0 = ck * 8;
  const int kt1 = (kt0 + 8 < nkt_all) ? kt0 + 8 : nkt_all;

  const int t = threadIdx.x, w = t >> 6, lane = t & 63;
  const int ql = lane & 31, hi = lane >> 5;
  const int q = qt * 128 + w * 32 + ql;      // absolute q row (2 lanes per q)
  const int qwave_max = qt * 128 + w * 32 + 31;

  const unsigned short* Kh = Kr + (size_t)kh * S_LEN * HD;
  const unsigned short* Vh = Vt + (size_t)kh * HD * S_LEN;

  bf16x8 qf[4];
#pragma unroll
  for (int c = 0; c < 4; ++c)
    qf[c] = *(const bf16x8*)(Qr + ((size_t)h * S_LEN + q) * HD + c * 16 + hi * 8);

  const int rsub = lane >> 3;
  const int cole = ((lane & 7) * 8) ^ (rsub << 3);

#define ASTAGE(b, kt) do {                                                           \
    int k0s = (kt) * 64;                                                             \
    _Pragma("unroll")                                                                \
    for (int c = 0; c < 4; ++c) {                                                    \
      int ch = w * 4 + c;                                                            \
      if (ch < 8)                                                                    \
        gload_lds16(Kh + (size_t)(k0s + ch * 8 + rsub) * HD + cole,                  \
                    &Ks[b][0][0] + ch * 512);                                        \
      else                                                                           \
        gload_lds16(Vh + (size_t)((ch - 8) * 8 + rsub) * S_LEN + k0s + cole,         \
                    &Vs[b][0][0] + (ch - 8) * 512);                                  \
    }                                                                                \
  } while (0)

  float m_run = -1e30f, l_run = 0.f;
  f32x16 oacc[2] = {};
  int cur = 0;
  ASTAGE(0, kt0);
  for (int kt = kt0; kt < kt1; ++kt) {
    __syncthreads();
    if (kt + 1 < kt1) ASTAGE(cur ^ 1, kt + 1);
    const int k0 = kt * 64;
    if (k0 <= qwave_max) {                   // skip fully-masked tiles (wave-uniform)
      f32x16 sacc[2] = {};
      __builtin_amdgcn_s_setprio(1);
#pragma unroll
      for (int tt = 0; tt < 2; ++tt)
#pragma unroll
        for (int c = 0; c < 4; ++c) {
          int row = tt * 32 + ql;
          bf16x8 kf = *(const bf16x8*)((const char*)&Ks[cur][0][0] + row * 128 +
                                       ((c * 32 + hi * 16) ^ ((ql & 7) << 4)));
          sacc[tt] = __builtin_amdgcn_mfma_f32_32x32x16_bf16(kf, qf[c], sacc[tt], 0, 0, 0);
        }
      __builtin_amdgcn_s_setprio(0);

      float p[32];
#pragma unroll
      for (int tt = 0; tt < 2; ++tt)
#pragma unroll
        for (int e = 0; e < 16; ++e) p[tt * 16 + e] = sacc[tt][e];

      if (k0 + 63 > q) {                     // diagonal tile: per-element mask
#pragma unroll
        for (int tt = 0; tt < 2; ++tt)
#pragma unroll
          for (int e = 0; e < 16; ++e) {
            int kl = tt * 32 + (e & 3) + 8 * (e >> 2) + 4 * hi;
            if (k0 + kl > q) p[tt * 16 + e] = -1e30f;
          }
      }

      float mx = p[0];
#pragma unroll
      for (int e = 1; e < 32; ++e) mx = fmaxf(mx, p[e]);
      mx = fmaxf(mx, __shfl_xor(mx, 32));

      if (__any(mx > m_run + 8.0f)) {        // defer-max (T13)
        float mnew = fmaxf(m_run, mx);
        float f = __expf(m_run - mnew);
        l_run *= f;
        oacc[0] *= f; oacc[1] *= f;
        m_run = mnew;
      }

      float lsum = 0.f;
#pragma unroll
      for (int e = 0; e < 32; ++e) { p[e] = __expf(p[e] - m_run); lsum += p[e]; }
      lsum += __shfl_xor(lsum, 32);
      l_run += lsum;

      unsigned g[16];
#pragma unroll
      for (int i = 0; i < 16; ++i) {
        union { __hip_bfloat162 b; unsigned u; } cv;
        cv.b = __float22bfloat162_rn(make_float2(p[2 * i], p[2 * i + 1]));
        g[i] = cv.u;
      }
#pragma unroll
      for (int b4 = 0; b4 < 16; b4 += 8) {
        asm volatile("v_permlane32_swap_b32 %0, %1" : "+v"(g[b4 + 0]), "+v"(g[b4 + 2]));
        asm volatile("v_permlane32_swap_b32 %0, %1" : "+v"(g[b4 + 1]), "+v"(g[b4 + 3]));
        asm volatile("v_permlane32_swap_b32 %0, %1" : "+v"(g[b4 + 4]), "+v"(g[b4 + 6]));
        asm volatile("v_permlane32_swap_b32 %0, %1" : "+v"(g[b4 + 5]), "+v"(g[b4 + 7]));
      }

#pragma unroll
      for (int s = 0; s < 4; ++s) {
        union { bf16x8 v; unsigned u[4]; } pf;
        pf.u[0] = g[s * 4 + 0]; pf.u[1] = g[s * 4 + 1];
        pf.u[2] = g[s * 4 + 2]; pf.u[3] = g[s * 4 + 3];
        __builtin_amdgcn_s_setprio(1);
#pragma unroll
        for (int dt = 0; dt < 2; ++dt) {
          int row = dt * 32 + ql;
          bf16x8 vf = *(const bf16x8*)((const char*)&Vs[cur][0][0] + row * 128 +
                                       ((s * 32 + hi * 16) ^ ((ql & 7) << 4)));
          oacc[dt] = __builtin_amdgcn_mfma_f32_32x32x16_bf16(vf, pf.v, oacc[dt], 0, 0, 0);
        }
        __builtin_amdgcn_s_setprio(0);
      }
    }
    cur ^= 1;
  }

  if (nch == 1) {
    float inv = 1.f / l_run;
#pragma unroll
    for (int dt = 0; dt < 2; ++dt)
#pragma unroll
      for (int gg = 0; gg < 4; ++gg) {
        ushort4 u;
        u.x = f2bf(oacc[dt][gg * 4 + 0] * inv);
        u.y = f2bf(oacc[dt][gg * 4 + 1] * inv);
        u.z = f2bf(oacc[dt][gg * 4 + 2] * inv);
        u.w = f2bf(oacc[dt][gg * 4 + 3] * inv);
        int d0 = dt * 32 + 8 * gg + 4 * hi;
        *(ushort4*)(Ob + (size_t)q * HIDN + h * HD + d0) = u;
      }
  } else {
    const int slot = (h * 16 + qt) * 4 + ck;
    float* ob = Opart + (size_t)slot * 8192 + t * 32;
#pragma unroll
    for (int dt = 0; dt < 2; ++dt)
#pragma unroll
      for (int gg = 0; gg < 4; ++gg) {
        f32x4 v4;
        v4[0] = oacc[dt][gg * 4 + 0]; v4[1] = oacc[dt][gg * 4 + 1];
        v4[2] = oacc[dt][gg * 4 + 2]; v4[3] = oacc[dt][gg * 4 + 3];
        *(f32x4*)(ob + dt * 16 + gg * 4) = v4;
      }
    if (hi == 0)
      *(float2*)(Mlpart + ((size_t)slot * 128 + w * 32 + ql) * 2) = make_float2(m_run, l_run);
  }
}

// ---------------- merge partials (qt>=4) -> bf16 Ob ----------------
__global__ __launch_bounds__(256) void attn_merge(const float* __restrict__ Opart,
                                                  const float* __restrict__ Mlpart,
                                                  unsigned short* __restrict__ Ob) {
  const int h = blockIdx.x & 15, qt = 4 + (blockIdx.x >> 4);
  const int nch = (2 * qt + 9) >> 3;
  const int slotb = (h * 16 + qt) * 4;
  const int t = threadIdx.x;
  const int ql = t & 31, hi = (t >> 5) & 1, w = t >> 6;
  const int q_l = w * 32 + ql;
  const int q = qt * 128 + q_l;

  float mc[4], lc[4], mstar = -1e30f;
#pragma unroll
  for (int c = 0; c < 4; ++c)
    if (c < nch) {
      float2 ml = *(const float2*)(Mlpart + ((size_t)(slotb + c) * 128 + q_l) * 2);
      mc[c] = ml.x; lc[c] = ml.y;
      mstar = fmaxf(mstar, ml.x);
    }
  float wgt[4], lsum = 0.f;
#pragma unroll
  for (int c = 0; c < 4; ++c)
    if (c < nch) { wgt[c] = __expf(mc[c] - mstar); lsum += wgt[c] * lc[c]; }
  const float inv = 1.f / lsum;

#pragma unroll
  for (int g = 0; g < 8; ++g) {
    f32x4 a = {};
#pragma unroll
    for (int c = 0; c < 4; ++c)
      if (c < nch) {
        f32x4 v = *(const f32x4*)(Opart + (size_t)(slotb + c) * 8192 + t * 32 + g * 4);
        a += v * wgt[c];
      }
    int dt = g >> 2, gg = g & 3;
    int d0 = dt * 32 + 8 * gg + 4 * hi;
    ushort4 u;
    u.x = f2bf(a[0] * inv); u.y = f2bf(a[1] * inv);
    u.z = f2bf(a[2] * inv); u.w = f2bf(a[3] * inv);
    *(ushort4*)(Ob + (size_t)q * HIDN + h * HD + d0) = u;
  }
}

extern "C" void kernel_launch(void* const* d_in, const int* in_sizes, int n_in,
                              void* d_out, int out_size, void* d_ws, size_t ws_size,
                              hipStream_t stream) {
  const float* hs = (const float*)d_in[0];
  // d_in[1] = attention_mask (deterministic causal; applied analytically)
  const int* pos = (const int*)d_in[2];
  const float* Wq = (const float*)d_in[3];
  const float* Wk = (const float*)d_in[4];
  const float* Wv = (const float*)d_in[5];
  const float* Wo = (const float*)d_in[6];
  float* out = (float*)d_out;

  char* ws = (char*)d_ws;
  unsigned short* hsb   = (unsigned short*)(ws);
  unsigned short* Wqkv  = (unsigned short*)(ws + 4194304);
  unsigned short* Wob   = (unsigned short*)(ws + 7340032);
  float2*         cstab = (float2*)(ws + 9437184);
  unsigned short* Qr    = (unsigned short*)(ws + 10485760);
  unsigned short* Kr    = (unsigned short*)(ws + 14680064);
  unsigned short* Vt    = (unsigned short*)(ws + 16777216);
  unsigned short* Ob    = (unsigned short*)(ws + 17825792);
  float*          Opart = (float*)(ws + 22020096);   // 1024 slots * 32KB = 32MB
  float*          Mlpart= (float*)(ws + 55574528);   // 1024 * 128 * 8B = 1MB

  dim3 blk(256);
  prep_kernel<<<4864, blk, 0, stream>>>(hs, Wq, Wk, Wv, Wo, pos, hsb, Wqkv, Wob, cstab);
  gemm_kernel<true><<<dim3(32, 12), blk, 0, stream>>>(hsb, Wqkv, nullptr, cstab, Qr, Kr, Vt);
  attn_part<<<640, blk, 0, stream>>>(Qr, Kr, Vt, Ob, Opart, Mlpart);
  attn_merge<<<192, blk, 0, stream>>>(Opart, Mlpart, Ob);
  gemm_kernel<false><<<dim3(32, 8), blk, 0, stream>>>(Ob, Wob, out, nullptr, nullptr, nullptr, nullptr);
}